// Round 9
// baseline (1852.581 us; speedup 1.0000x reference)
//
#include <hip/hip_runtime.h>

#define DI __device__ __forceinline__

typedef short s16x4 __attribute__((ext_vector_type(4)));
typedef short s16x8 __attribute__((ext_vector_type(8)));
typedef float f32x4 __attribute__((ext_vector_type(4)));
typedef unsigned int u32x4 __attribute__((ext_vector_type(4)));

constexpr int CB = 64, CL = 512, CV = 256, CE = 512, CH = 1024;
constexpr int CBL = CB * CL;                // 32768
constexpr size_t LOGN = (size_t)CBL * CV;   // 8388608 floats of logits

// ---- workspace layout (bytes) ----
constexpr size_t WS_H     = 4096;                           // (unused in v8; kept for layout)
constexpr size_t WS_EMBB  = WS_H    + 2u*CB*CH*2;           // emb bf16   256*512*2
constexpr size_t WS_UWB   = WS_EMBB + (size_t)CV*CE*2;      // U_w bf16   1024*512*2
constexpr size_t WS_VWB   = WS_UWB  + (size_t)CH*CE*2;      // V_w bf16   1024*1024*2
constexpr size_t WS_DECWB = WS_VWB  + (size_t)CH*CH*2;      // dec_w bf16 256*1024*2
constexpr size_t WS_UX    = WS_DECWB+ (size_t)CV*CH*2;      // Ux bf16    32768*1024*2
constexpr size_t WS_HS    = WS_UX   + (size_t)CBL*CH*2;     // hs bf16    32768*1024*2

DI unsigned short f2bf(float f) {            // RNE f32 -> bf16
  unsigned u = __float_as_uint(f);
  u += 0x7FFFu + ((u >> 16) & 1u);
  return (unsigned short)(u >> 16);
}
DI float bf2f(unsigned short h) { return __uint_as_float(((unsigned)h) << 16); }

DI f32x4 mfma_bf16(s16x8 a, s16x8 b, f32x4 c) {
  return __builtin_amdgcn_mfma_f32_16x16x32_bf16(a, b, c, 0, 0, 0);
}

DI float fast_tanh(float x) {
  float a = fminf(fabsf(x), 20.0f);
  float e = __expf(-2.0f * a);
  float r = (1.0f - e) / (1.0f + e);
  return __builtin_copysignf(r, x);   // |r| < 1 always -> bf16 never 0xFFFF
}

// ---------------- convert f32 weights -> bf16 in ws ----------------
__global__ __launch_bounds__(256) void k_convert(
    const float* __restrict__ emb, const float* __restrict__ uw,
    const float* __restrict__ vw,  const float* __restrict__ dw,
    unsigned short* __restrict__ embb, unsigned short* __restrict__ uwb,
    unsigned short* __restrict__ vwb,  unsigned short* __restrict__ dwb)
{
  int i = (blockIdx.x * 256 + threadIdx.x) * 4;   // 1966080 elems total, grid exact
  const float* s; unsigned short* d; int off;
  if      (i < 131072)  { s = emb; d = embb; off = i; }
  else if (i < 655360)  { s = uw;  d = uwb;  off = i - 131072; }
  else if (i < 1703936) { s = vw;  d = vwb;  off = i - 655360; }
  else                  { s = dw;  d = dwb;  off = i - 1703936; }
  float4 v = *(const float4*)(s + off);
  ushort4 o; o.x = f2bf(v.x); o.y = f2bf(v.y); o.z = f2bf(v.z); o.w = f2bf(v.w);
  *(ushort4*)(d + off) = o;
}

// ---------------- generic bf16 MFMA GEMM: C[r, n] = sum_k A[r,k]*B[n,k] ----------------
template<int KD, int NT, bool GATHER, bool OUTF32>
__global__ __launch_bounds__(256) void k_gemm(
    const unsigned short* __restrict__ Asrc,
    const int* __restrict__ xidx,
    const unsigned short* __restrict__ Bsrc,
    const float* __restrict__ biasv,
    unsigned short* __restrict__ Cb,
    float* __restrict__ Cf)
{
  __shared__ unsigned char As[64 * 128];
  __shared__ unsigned char Bs[64 * 128];
  __shared__ int xs[64];

  const int tid = threadIdx.x;
  const int rt = blockIdx.x, ct = blockIdx.y;
  const int r0 = rt * 64, c0 = ct * 64;

  if (GATHER) {
    if (tid < 64) xs[tid] = xidx[r0 + tid];
    __syncthreads();
  }

  const int r  = tid >> 2, kq = tid & 3;
  const unsigned short* aRow = GATHER ? (Asrc + (size_t)xs[r] * KD)
                                      : (Asrc + (size_t)(r0 + r) * KD);
  const unsigned short* bRow = Bsrc + (size_t)(c0 + r) * KD;
  const int dstOff = r * 128 + ((kq * 16) ^ ((r & 7) << 4));

  const int wave = tid >> 6, lane = tid & 63;
  const int ln15 = lane & 15, lg = lane >> 4;
  const int xr = (lane & 7) << 4;
  int aOff[4];
#pragma unroll
  for (int m = 0; m < 4; ++m) aOff[m] = (m * 16 + ln15) * 128 + ((lg * 16) ^ xr);
  const int bOff = (wave * 16 + ln15) * 128 + ((lg * 16) ^ xr);

  f32x4 acc[4] = {};
  for (int kk = 0; kk < KD / 32; ++kk) {
    s16x8 av = *(const s16x8*)(aRow + kk * 32 + kq * 8);
    s16x8 bv = *(const s16x8*)(bRow + kk * 32 + kq * 8);
    __syncthreads();
    *(s16x8*)(As + dstOff) = av;
    *(s16x8*)(Bs + dstOff) = bv;
    __syncthreads();
    s16x8 bf = *(const s16x8*)(Bs + bOff);
#pragma unroll
    for (int m = 0; m < 4; ++m) {
      s16x8 af = *(const s16x8*)(As + aOff[m]);
      acc[m] = mfma_bf16(af, bf, acc[m]);
    }
  }

  const int colg = c0 + wave * 16 + ln15;
  float bv = 0.f;
  if (OUTF32) bv = biasv[colg];
#pragma unroll
  for (int m = 0; m < 4; ++m) {
#pragma unroll
    for (int rr = 0; rr < 4; ++rr) {
      int rowg = r0 + m * 16 + lg * 4 + rr;
      if (OUTF32) Cf[(size_t)rowg * NT + colg] = acc[m][rr] + bv;
      else        Cb[(size_t)rowg * NT + colg] = f2bf(acc[m][rr]);
    }
  }
}

// ---------------- persistent recurrence, v8: hs as depth-512 ring ----------------
// 64 wgs x 256 thr. wg=(bg,cs): batches bg*16..+16, cols cs*64..+64.
// No flags, no fences, no poison-after-read. hs[B][L][H] is pre-poisoned
// 0xFFFF (bf16 -NaN; tanh output can never encode it). Every hs cell is
// written exactly once -> no staleness. Produce = ONE 8B fire-and-forget
// sc0sc1 store into hs (doubles as the persisted output). Consume = poll
// your own 8 chunks of hs[:,t-1,:] until NaN-free (non-destructive; any
// number of readers). Partial store arrival handled by per-chunk retry.
__global__ __launch_bounds__(256, 1) void k_rec(
    const unsigned short* __restrict__ vwb,   // [H][H] bf16
    const unsigned short* __restrict__ ux,    // [B][L][H] bf16
    unsigned short* __restrict__ hs,          // [B][L][H] bf16 (pre-poisoned)
    const float* __restrict__ alpha, const float* __restrict__ beta1,
    const float* __restrict__ beta2, const float* __restrict__ bias,
    float* __restrict__ out)
{
  __shared__ __align__(16) unsigned char hlds[2][16 * 2048];   // 2 x 32 KiB

  const int w = blockIdx.x;
  const int bg = w >> 4, cs = w & 15;       // batch-group, col-slice
  const int tid = threadIdx.x;
  const int wave = tid >> 6, lane = tid & 63;
  const int ln15 = lane & 15, lg = lane >> 4;
  const int b0 = bg * 16;
  // operand-swapped MFMA mapping (A=V_w, B=h):
  //   lane's batch (D col = lane&15) = b0+ln15; lane's 4 V-cols (D rows) = colbase..+3
  const int colbase = cs * 64 + wave * 16 + lg * 4;
  const int myb = b0 + ln15;

  // A-operand resident: breg[kc] lane l = V_w[cs*64+wave*16+(l&15)][kc*32+(l>>4)*8..+8]
  s16x8 breg[32];
  {
    const unsigned short* vrow = vwb + (size_t)(cs * 64 + wave * 16 + ln15) * CH + lg * 8;
#pragma unroll
    for (int kc = 0; kc < 32; ++kc) breg[kc] = *(const s16x8*)(vrow + kc * 32);
  }
#pragma unroll
  for (int kc = 0; kc < 32; ++kc) asm volatile("" : "+v"(breg[kc]));  // pin (R5 win)

  const float4 alv = *(const float4*)(alpha + colbase);
  const float4 b1v = *(const float4*)(beta1 + colbase);
  const float4 b2v = *(const float4*)(beta2 + colbase);
  const float4 biv = *(const float4*)(bias  + colbase);

  // descriptor over all of hs (64 MiB); polls/loads aux=17 (SC0|SC1)
  __amdgpu_buffer_rsrc_t hsrd = __builtin_amdgcn_make_buffer_rsrc(
      (void*)hs, (short)0, (int)((size_t)CBL * CH * 2), 0x00020000);

  // staging: thread stages 8 x 16B chunks of the group's h(t-1) slice.
  // chunk i: local batch row r=2i+(tid>>7), row-bytes (tid&127)*16.
  // hs byte addr = (b0+r)*CL*2048 + (t-1)*2048 + (tid&127)*16
  int rowByte[8], sRow[8], sCol[8];
#pragma unroll
  for (int i = 0; i < 8; ++i) {
    const int r = 2 * i + (tid >> 7);
    sRow[i] = r;
    sCol[i] = ((tid & 127) * 16) ^ ((r & 7) << 4);
    rowByte[i] = (b0 + r) * (CL * 2048) + (tid & 127) * 16;
  }

  // fragment reads (B = h): local batch row ln15, k-chunk lg*8
  const int fBase = ln15 * 2048;
  const int fXor  = (ln15 & 7) << 4;

  s16x4 uxv = *(const s16x4*)(ux + ((size_t)myb * CL + 0) * CH + colbase);

  for (int t = 0; t < CL; ++t) {
    f32x4 vh = {};
    if (t > 0) {
      const int coff = (t - 1) * 2048;
      unsigned char* lb = hlds[t & 1];

      // ---- poll-validate my 8 chunks of hs[:,t-1,:] (data IS the signal) ----
      s16x8 stg[8];
      unsigned okm = 0;
      do {
#pragma unroll
        for (int i = 0; i < 8; ++i) if (!((okm >> i) & 1u)) {
          auto raw = __builtin_amdgcn_raw_buffer_load_b128(
              hsrd, rowByte[i] + coff, 0, 17);
          stg[i] = __builtin_bit_cast(s16x8, raw);
        }
        asm volatile("" ::: "memory");   // force re-load next sweep
#pragma unroll
        for (int i = 0; i < 8; ++i) if (!((okm >> i) & 1u)) {
          u32x4 wv = __builtin_bit_cast(u32x4, stg[i]);
          bool bad = false;
#pragma unroll
          for (int j = 0; j < 4; ++j) {
            unsigned q = wv[j];
            bad = bad | ((q & 0xFFFFu) == 0xFFFFu) | ((q >> 16) == 0xFFFFu);
          }
          if (!bad) okm |= 1u << i;
        }
        if (okm != 0xFFu) __builtin_amdgcn_s_sleep(1);
      } while (okm != 0xFFu);

      // ---- stage to LDS (double-buffered; one barrier per step) ----
#pragma unroll
      for (int i = 0; i < 8; ++i)
        *(s16x8*)(lb + sRow[i] * 2048 + sCol[i]) = stg[i];
      __syncthreads();

      // ---- fragments + MFMA, A=V_w (resident), B=h, 4 chains ----
      f32x4 a0 = {}, a1 = {}, a2 = {}, a3 = {};
#pragma unroll
      for (int kc = 0; kc < 32; kc += 4) {
        s16x8 f0 = *(const s16x8*)(lb + fBase + ((lg * 16 + kc * 64)       ^ fXor));
        s16x8 f1 = *(const s16x8*)(lb + fBase + ((lg * 16 + kc * 64 + 64)  ^ fXor));
        s16x8 f2 = *(const s16x8*)(lb + fBase + ((lg * 16 + kc * 64 + 128) ^ fXor));
        s16x8 f3 = *(const s16x8*)(lb + fBase + ((lg * 16 + kc * 64 + 192) ^ fXor));
        a0 = mfma_bf16(breg[kc],     f0, a0);
        a1 = mfma_bf16(breg[kc + 1], f1, a1);
        a2 = mfma_bf16(breg[kc + 2], f2, a2);
        a3 = mfma_bf16(breg[kc + 3], f3, a3);
      }
      vh = (a0 + a1) + (a2 + a3);
    }

    // ---- pointwise: vh[rr] = (V h)[col colbase+rr] for batch myb ----
    float hnv[4]; unsigned short hbv[4];
#pragma unroll
    for (int rr = 0; rr < 4; ++rr) {
      const float u = bf2f((unsigned short)uxv[rr]);
      const float v = vh[rr];
      const float mm = (&alv.x)[rr] * (v * u) + (&b1v.x)[rr] * v +
                       (&b2v.x)[rr] * u + (&biv.x)[rr];
      hnv[rr] = fast_tanh(mm);
      hbv[rr] = f2bf(hnv[rr]);
    }

    const unsigned long long pk = (unsigned long long)hbv[0]
                                | ((unsigned long long)hbv[1] << 16)
                                | ((unsigned long long)hbv[2] << 32)
                                | ((unsigned long long)hbv[3] << 48);
    char* hp = (char*)hs + (size_t)myb * (CL * 2048) + t * 2048 + colbase * 2;

    if (t < CL - 1) {
      // produce = the hs store: fire-and-forget, sc0sc1 (write-through to L3)
      __hip_atomic_store((unsigned long long*)hp, pk,
                         __ATOMIC_RELAXED, __HIP_MEMORY_SCOPE_SYSTEM);
      // off critical path: next-step ux prefetch (normal cached)
      uxv = *(const s16x4*)(ux + ((size_t)myb * CL + (t + 1)) * CH + colbase);
    } else {
      // last step: nobody polls it — plain store + final-h output
      *(unsigned long long*)hp = pk;
      float4 o; o.x = hnv[0]; o.y = hnv[1]; o.z = hnv[2]; o.w = hnv[3];
      *(float4*)(out + LOGN + (size_t)myb * CH + colbase) = o;
    }
  }
}

extern "C" void kernel_launch(void* const* d_in, const int* in_sizes, int n_in,
                              void* d_out, int out_size, void* d_ws, size_t ws_size,
                              hipStream_t stream) {
  const int*   x     = (const int*)  d_in[0];
  const float* emb   = (const float*)d_in[1];
  const float* Uw    = (const float*)d_in[2];
  const float* Vw    = (const float*)d_in[3];
  const float* alpha = (const float*)d_in[4];
  const float* beta1 = (const float*)d_in[5];
  const float* beta2 = (const float*)d_in[6];
  const float* bias  = (const float*)d_in[7];
  const float* decw  = (const float*)d_in[8];
  const float* decb  = (const float*)d_in[9];
  float* out = (float*)d_out;
  char*  ws  = (char*)d_ws;

  unsigned short* embb  = (unsigned short*)(ws + WS_EMBB);
  unsigned short* uwb   = (unsigned short*)(ws + WS_UWB);
  unsigned short* vwb   = (unsigned short*)(ws + WS_VWB);
  unsigned short* dwb   = (unsigned short*)(ws + WS_DECWB);
  unsigned short* uxb   = (unsigned short*)(ws + WS_UX);
  unsigned short* hsb   = (unsigned short*)(ws + WS_HS);

  // pre-poison ALL of hs with bf16 -NaN (0xFFFF): depth-512 ring, every cell
  // written exactly once by k_rec -> no staleness, no flags, no fences.
  (void)hipMemsetAsync(ws + WS_HS, 0xFF, (size_t)CBL * CH * 2, stream);

  k_convert<<<1920, 256, 0, stream>>>(emb, Uw, Vw, decw, embb, uwb, vwb, dwb);

  k_gemm<CE, CH, true, false><<<dim3(CBL / 64, CH / 64), 256, 0, stream>>>(
      embb, x, uwb, nullptr, uxb, nullptr);

  k_rec<<<64, 256, 0, stream>>>(vwb, uxb, hsb, alpha, beta1, beta2, bias, out);

  k_gemm<CH, CV, false, true><<<dim3(CBL / 64, CV / 64), 256, 0, stream>>>(
      hsb, nullptr, dwb, decb, nullptr, out);
}

// Round 10
// 1834.561 us; speedup vs baseline: 1.0098x; 1.0098x over previous
//
#include <hip/hip_runtime.h>

#define DI __device__ __forceinline__

typedef short s16x4 __attribute__((ext_vector_type(4)));
typedef short s16x8 __attribute__((ext_vector_type(8)));
typedef float f32x4 __attribute__((ext_vector_type(4)));
typedef unsigned int u32x4 __attribute__((ext_vector_type(4)));

constexpr int CB = 64, CL = 512, CV = 256, CE = 512, CH = 1024;
constexpr int CBL = CB * CL;                // 32768
constexpr size_t LOGN = (size_t)CBL * CV;   // 8388608 floats of logits
constexpr unsigned SLOT = (unsigned)CB * CH * 2;   // 128 KiB per ring slot

// ---- workspace layout (bytes) ----
constexpr size_t WS_RING  = 4096;                           // 4-slot ring: 512 KiB
constexpr size_t WS_EMBB  = WS_RING + 4u*SLOT;              // emb bf16   256*512*2
constexpr size_t WS_UWB   = WS_EMBB + (size_t)CV*CE*2;      // U_w bf16   1024*512*2
constexpr size_t WS_VWB   = WS_UWB  + (size_t)CH*CE*2;      // V_w bf16   1024*1024*2
constexpr size_t WS_DECWB = WS_VWB  + (size_t)CH*CH*2;      // dec_w bf16 256*1024*2
constexpr size_t WS_UX    = WS_DECWB+ (size_t)CV*CH*2;      // Ux bf16    32768*1024*2
constexpr size_t WS_HS    = WS_UX   + (size_t)CBL*CH*2;     // hs bf16    32768*1024*2

DI unsigned short f2bf(float f) {            // RNE f32 -> bf16
  unsigned u = __float_as_uint(f);
  u += 0x7FFFu + ((u >> 16) & 1u);
  return (unsigned short)(u >> 16);
}
DI float bf2f(unsigned short h) { return __uint_as_float(((unsigned)h) << 16); }

DI f32x4 mfma_bf16(s16x8 a, s16x8 b, f32x4 c) {
  return __builtin_amdgcn_mfma_f32_16x16x32_bf16(a, b, c, 0, 0, 0);
}

DI float fast_tanh(float x) {
  float a = fminf(fabsf(x), 20.0f);
  float e = __expf(-2.0f * a);
  float r = (1.0f - e) / (1.0f + e);
  return __builtin_copysignf(r, x);   // |r| < 1 always -> bf16 never 0xFFFF
}

// ---------------- convert f32 weights -> bf16 in ws ----------------
__global__ __launch_bounds__(256) void k_convert(
    const float* __restrict__ emb, const float* __restrict__ uw,
    const float* __restrict__ vw,  const float* __restrict__ dw,
    unsigned short* __restrict__ embb, unsigned short* __restrict__ uwb,
    unsigned short* __restrict__ vwb,  unsigned short* __restrict__ dwb)
{
  int i = (blockIdx.x * 256 + threadIdx.x) * 4;   // 1966080 elems total, grid exact
  const float* s; unsigned short* d; int off;
  if      (i < 131072)  { s = emb; d = embb; off = i; }
  else if (i < 655360)  { s = uw;  d = uwb;  off = i - 131072; }
  else if (i < 1703936) { s = vw;  d = vwb;  off = i - 655360; }
  else                  { s = dw;  d = dwb;  off = i - 1703936; }
  float4 v = *(const float4*)(s + off);
  ushort4 o; o.x = f2bf(v.x); o.y = f2bf(v.y); o.z = f2bf(v.z); o.w = f2bf(v.w);
  *(ushort4*)(d + off) = o;
}

// ---------------- generic bf16 MFMA GEMM: C[r, n] = sum_k A[r,k]*B[n,k] ----------------
template<int KD, int NT, bool GATHER, bool OUTF32>
__global__ __launch_bounds__(256) void k_gemm(
    const unsigned short* __restrict__ Asrc,
    const int* __restrict__ xidx,
    const unsigned short* __restrict__ Bsrc,
    const float* __restrict__ biasv,
    unsigned short* __restrict__ Cb,
    float* __restrict__ Cf)
{
  __shared__ unsigned char As[64 * 128];
  __shared__ unsigned char Bs[64 * 128];
  __shared__ int xs[64];

  const int tid = threadIdx.x;
  const int rt = blockIdx.x, ct = blockIdx.y;
  const int r0 = rt * 64, c0 = ct * 64;

  if (GATHER) {
    if (tid < 64) xs[tid] = xidx[r0 + tid];
    __syncthreads();
  }

  const int r  = tid >> 2, kq = tid & 3;
  const unsigned short* aRow = GATHER ? (Asrc + (size_t)xs[r] * KD)
                                      : (Asrc + (size_t)(r0 + r) * KD);
  const unsigned short* bRow = Bsrc + (size_t)(c0 + r) * KD;
  const int dstOff = r * 128 + ((kq * 16) ^ ((r & 7) << 4));

  const int wave = tid >> 6, lane = tid & 63;
  const int ln15 = lane & 15, lg = lane >> 4;
  const int xr = (lane & 7) << 4;
  int aOff[4];
#pragma unroll
  for (int m = 0; m < 4; ++m) aOff[m] = (m * 16 + ln15) * 128 + ((lg * 16) ^ xr);
  const int bOff = (wave * 16 + ln15) * 128 + ((lg * 16) ^ xr);

  f32x4 acc[4] = {};
  for (int kk = 0; kk < KD / 32; ++kk) {
    s16x8 av = *(const s16x8*)(aRow + kk * 32 + kq * 8);
    s16x8 bv = *(const s16x8*)(bRow + kk * 32 + kq * 8);
    __syncthreads();
    *(s16x8*)(As + dstOff) = av;
    *(s16x8*)(Bs + dstOff) = bv;
    __syncthreads();
    s16x8 bf = *(const s16x8*)(Bs + bOff);
#pragma unroll
    for (int m = 0; m < 4; ++m) {
      s16x8 af = *(const s16x8*)(As + aOff[m]);
      acc[m] = mfma_bf16(af, bf, acc[m]);
    }
  }

  const int colg = c0 + wave * 16 + ln15;
  float bv = 0.f;
  if (OUTF32) bv = biasv[colg];
#pragma unroll
  for (int m = 0; m < 4; ++m) {
#pragma unroll
    for (int rr = 0; rr < 4; ++rr) {
      int rowg = r0 + m * 16 + lg * 4 + rr;
      if (OUTF32) Cf[(size_t)rowg * NT + colg] = acc[m][rr] + bv;
      else        Cb[(size_t)rowg * NT + colg] = f2bf(acc[m][rr]);
    }
  }
}

// ------------- persistent recurrence, v9: 4-slot NaN-signal hot ring -------------
// 64 wgs x 256 thr. wg=(bg,cs): batches bg*16..+16, cols cs*64..+64.
// Ring[4][B][H] bf16, 512 KiB, pre-poisoned 0xFFFF. h(t) -> slot t&3.
// Consume(t): poll own 8 chunks of slot (t-1)&3 until NaN-free (non-destructive,
//   any readers) -> LDS -> MFMA (A=V_w pinned in 128 VGPR, B=h, 4 chains).
// Poison: after the post-staging syncthreads (wg-wide proof that ALL 16 peer
//   wgs produced h(t-1), hence finished reading h(t-2)), each thread poisons
//   ITS OWN cell in slot (t+2)&3 (which held h(t-2)). vmcnt(0) before produce
//   orders poison < produce; L3 causality then guarantees a consumer that
//   sees h(t) also sees every poison drained before it -> pollers of slot s
//   at step t+3 see poison-or-h(t+2), never stale h(t-2).
// Produce(t): ONE 8B fire-and-forget sc0sc1 store into slot t&3.
// No flags, no fences, no destructive reads; deadlock class eliminated.
__global__ __launch_bounds__(256, 1) void k_rec(
    const unsigned short* __restrict__ vwb,   // [H][H] bf16
    const unsigned short* __restrict__ ux,    // [B][L][H] bf16
    unsigned short* __restrict__ ring,        // [4][B][H] bf16 (pre-poisoned)
    unsigned short* __restrict__ hs,          // [B][L][H] bf16
    const float* __restrict__ alpha, const float* __restrict__ beta1,
    const float* __restrict__ beta2, const float* __restrict__ bias,
    float* __restrict__ out)
{
  __shared__ __align__(16) unsigned char hlds[2][16 * 2048];   // 2 x 32 KiB

  const int w = blockIdx.x;
  const int bg = w >> 4, cs = w & 15;       // batch-group, col-slice
  const int tid = threadIdx.x;
  const int wave = tid >> 6, lane = tid & 63;
  const int ln15 = lane & 15, lg = lane >> 4;
  const int b0 = bg * 16;
  // swapped-operand mapping (validated in v8): lane's batch = b0+ln15;
  // lane's 4 V-cols = colbase..+3
  const int colbase = cs * 64 + wave * 16 + lg * 4;
  const int myb = b0 + ln15;

  // A-operand resident: breg[kc] lane l = V_w[cs*64+wave*16+(l&15)][kc*32+(l>>4)*8..+8]
  s16x8 breg[32];
  {
    const unsigned short* vrow = vwb + (size_t)(cs * 64 + wave * 16 + ln15) * CH + lg * 8;
#pragma unroll
    for (int kc = 0; kc < 32; ++kc) breg[kc] = *(const s16x8*)(vrow + kc * 32);
  }
#pragma unroll
  for (int kc = 0; kc < 32; ++kc) asm volatile("" : "+v"(breg[kc]));  // pin (R5 win)

  const float4 alv = *(const float4*)(alpha + colbase);
  const float4 b1v = *(const float4*)(beta1 + colbase);
  const float4 b2v = *(const float4*)(beta2 + colbase);
  const float4 biv = *(const float4*)(bias  + colbase);

  // ring descriptor; all ring traffic aux=17 (SC0|SC1): L1/L2-bypass, L3-coherent
  __amdgpu_buffer_rsrc_t rsrd = __builtin_amdgcn_make_buffer_rsrc(
      (void*)ring, (short)0, (int)(4u * SLOT), 0x00020000);

  // staging (R6-validated): thread stages 8 x 16B, all from producer (tid&127)>>3
  // LDS identity: hlds[row][col ^ ((row&7)<<4)] = ring_slot[b0+row][col]
  int sRow[8], sCol[8];
#pragma unroll
  for (int i = 0; i < 8; ++i) {
    const int L = i * 4096 + tid * 16;
    sRow[i] = L >> 11;
    sCol[i] = (L & 2047) ^ ((sRow[i] & 7) << 4);
  }
  const unsigned stgBase = (unsigned)(b0 * 2048);

  // fragment reads (B = h): LDS row ln15, k-chunk lg*8 (+kc*32)
  const int fBase = ln15 * 2048;
  const int fXor  = (ln15 & 7) << 4;

  // my produced/poisoned cell offset within a slot (bytes)
  const unsigned cellOff = (unsigned)(myb * 2048 + colbase * 2);

  s16x4 uxv = *(const s16x4*)(ux + ((size_t)myb * CL + 0) * CH + colbase);

  for (int t = 0; t < CL; ++t) {
    f32x4 vh = {};
    if (t > 0) {
      const unsigned roff = ((unsigned)((t - 1) & 3)) * SLOT + stgBase;
      unsigned char* lb = hlds[t & 1];

      // ---- poll-validate my 8 chunks of slot (t-1)&3 (data IS the signal) ----
      s16x8 stg[8];
      unsigned okm = 0;
      do {
#pragma unroll
        for (int i = 0; i < 8; ++i) if (!((okm >> i) & 1u)) {
          auto raw = __builtin_amdgcn_raw_buffer_load_b128(
              rsrd, (int)(roff + i * 4096 + tid * 16), 0, 17);
          stg[i] = __builtin_bit_cast(s16x8, raw);
        }
        asm volatile("" ::: "memory");   // force re-load next sweep
#pragma unroll
        for (int i = 0; i < 8; ++i) if (!((okm >> i) & 1u)) {
          u32x4 wv = __builtin_bit_cast(u32x4, stg[i]);
          bool bad = false;
#pragma unroll
          for (int j = 0; j < 4; ++j) {
            unsigned q = wv[j];
            bad = bad | ((q & 0xFFFFu) == 0xFFFFu) | ((q >> 16) == 0xFFFFu);
          }
          if (!bad) okm |= 1u << i;
        }
        if (okm != 0xFFu) __builtin_amdgcn_s_sleep(1);
      } while (okm != 0xFFu);

      // ---- stage to LDS (double-buffered) ----
#pragma unroll
      for (int i = 0; i < 8; ++i)
        *(s16x8*)(lb + sRow[i] * 2048 + sCol[i]) = stg[i];
      __syncthreads();   // wg-wide: all producers of h(t-1) seen -> peers past h(t-2) reads

      // ---- poison own cell of slot (t+2)&3 (holds h(t-2)); ack covered by MFMA ----
      {
        unsigned long long* pz = (unsigned long long*)
            ((char*)ring + (size_t)((t + 2) & 3) * SLOT + cellOff);
        __hip_atomic_store(pz, ~0ull, __ATOMIC_RELAXED, __HIP_MEMORY_SCOPE_SYSTEM);
      }

      // ---- fragments + MFMA, A=V_w (resident), B=h, 4 chains ----
      f32x4 a0 = {}, a1 = {}, a2 = {}, a3 = {};
#pragma unroll
      for (int kc = 0; kc < 32; kc += 4) {
        s16x8 f0 = *(const s16x8*)(lb + fBase + ((lg * 16 + kc * 64)       ^ fXor));
        s16x8 f1 = *(const s16x8*)(lb + fBase + ((lg * 16 + kc * 64 + 64)  ^ fXor));
        s16x8 f2 = *(const s16x8*)(lb + fBase + ((lg * 16 + kc * 64 + 128) ^ fXor));
        s16x8 f3 = *(const s16x8*)(lb + fBase + ((lg * 16 + kc * 64 + 192) ^ fXor));
        a0 = mfma_bf16(breg[kc],     f0, a0);
        a1 = mfma_bf16(breg[kc + 1], f1, a1);
        a2 = mfma_bf16(breg[kc + 2], f2, a2);
        a3 = mfma_bf16(breg[kc + 3], f3, a3);
      }
      vh = (a0 + a1) + (a2 + a3);
    }

    // ---- pointwise ----
    float hnv[4]; unsigned short hbv[4];
#pragma unroll
    for (int rr = 0; rr < 4; ++rr) {
      const float u = bf2f((unsigned short)uxv[rr]);
      const float v = vh[rr];
      const float mm = (&alv.x)[rr] * (v * u) + (&b1v.x)[rr] * v +
                       (&b2v.x)[rr] * u + (&biv.x)[rr];
      hnv[rr] = fast_tanh(mm);
      hbv[rr] = f2bf(hnv[rr]);
    }

    const unsigned long long pk = (unsigned long long)hbv[0]
                                | ((unsigned long long)hbv[1] << 16)
                                | ((unsigned long long)hbv[2] << 32)
                                | ((unsigned long long)hbv[3] << 48);

    if (t < CL - 1) {
      // order: poison (and all prior VM) acked at L3 before produce issues
      asm volatile("s_waitcnt vmcnt(0)" ::: "memory");
      unsigned long long* hp = (unsigned long long*)
          ((char*)ring + (size_t)(t & 3) * SLOT + cellOff);
      __hip_atomic_store(hp, pk, __ATOMIC_RELAXED, __HIP_MEMORY_SCOPE_SYSTEM);
      // off critical path: hs persist + next ux prefetch (normal cached)
      *(unsigned long long*)(hs + ((size_t)myb * CL + t) * CH + colbase) = pk;
      uxv = *(const s16x4*)(ux + ((size_t)myb * CL + (t + 1)) * CH + colbase);
    } else {
      // last step: no consumer — just persist + final-h output
      *(unsigned long long*)(hs + ((size_t)myb * CL + t) * CH + colbase) = pk;
      float4 o; o.x = hnv[0]; o.y = hnv[1]; o.z = hnv[2]; o.w = hnv[3];
      *(float4*)(out + LOGN + (size_t)myb * CH + colbase) = o;
    }
  }
}

extern "C" void kernel_launch(void* const* d_in, const int* in_sizes, int n_in,
                              void* d_out, int out_size, void* d_ws, size_t ws_size,
                              hipStream_t stream) {
  const int*   x     = (const int*)  d_in[0];
  const float* emb   = (const float*)d_in[1];
  const float* Uw    = (const float*)d_in[2];
  const float* Vw    = (const float*)d_in[3];
  const float* alpha = (const float*)d_in[4];
  const float* beta1 = (const float*)d_in[5];
  const float* beta2 = (const float*)d_in[6];
  const float* bias  = (const float*)d_in[7];
  const float* decw  = (const float*)d_in[8];
  const float* decb  = (const float*)d_in[9];
  float* out = (float*)d_out;
  char*  ws  = (char*)d_ws;

  unsigned short* ring  = (unsigned short*)(ws + WS_RING);
  unsigned short* embb  = (unsigned short*)(ws + WS_EMBB);
  unsigned short* uwb   = (unsigned short*)(ws + WS_UWB);
  unsigned short* vwb   = (unsigned short*)(ws + WS_VWB);
  unsigned short* dwb   = (unsigned short*)(ws + WS_DECWB);
  unsigned short* uxb   = (unsigned short*)(ws + WS_UX);
  unsigned short* hsb   = (unsigned short*)(ws + WS_HS);

  // pre-poison the 512 KiB ring with bf16 -NaN (0xFFFF) every call (graph-safe)
  (void)hipMemsetAsync(ws + WS_RING, 0xFF, 4u * SLOT, stream);

  k_convert<<<1920, 256, 0, stream>>>(emb, Uw, Vw, decw, embb, uwb, vwb, dwb);

  k_gemm<CE, CH, true, false><<<dim3(CBL / 64, CH / 64), 256, 0, stream>>>(
      embb, x, uwb, nullptr, uxb, nullptr);

  k_rec<<<64, 256, 0, stream>>>(vwb, uxb, ring, hsb, alpha, beta1, beta2, bias, out);

  k_gemm<CH, CV, false, true><<<dim3(CBL / 64, CV / 64), 256, 0, stream>>>(
      hsb, nullptr, dwb, decb, nullptr, out);
}

// Round 11
// 1630.557 us; speedup vs baseline: 1.1362x; 1.1251x over previous
//
#include <hip/hip_runtime.h>

#define DI __device__ __forceinline__

typedef short s16x4 __attribute__((ext_vector_type(4)));
typedef short s16x8 __attribute__((ext_vector_type(8)));
typedef float f32x4 __attribute__((ext_vector_type(4)));

constexpr int CB = 64, CL = 512, CV = 256, CE = 512, CH = 1024;
constexpr int CBL = CB * CL;                // 32768
constexpr size_t LOGN = (size_t)CBL * CV;   // 8388608 floats of logits
constexpr unsigned SLOT = (unsigned)CB * CH * 2;   // 128 KiB per ring slot

// ---- workspace layout (bytes) ----
constexpr size_t WS_BAR   = 0;                              // flags: 4 groups x 64 ints
constexpr size_t WS_RING  = 4096;                           // 2-slot ring: 256 KiB
constexpr size_t WS_EMBB  = WS_RING + 2u*SLOT;              // emb bf16   256*512*2
constexpr size_t WS_UWB   = WS_EMBB + (size_t)CV*CE*2;      // U_w bf16   1024*512*2
constexpr size_t WS_VWB   = WS_UWB  + (size_t)CH*CE*2;      // V_w bf16   1024*1024*2
constexpr size_t WS_DECWB = WS_VWB  + (size_t)CH*CH*2;      // dec_w bf16 256*1024*2
constexpr size_t WS_UX    = WS_DECWB+ (size_t)CV*CH*2;      // Ux bf16    32768*1024*2
constexpr size_t WS_HS    = WS_UX   + (size_t)CBL*CH*2;     // hs bf16    32768*1024*2

DI unsigned short f2bf(float f) {            // RNE f32 -> bf16
  unsigned u = __float_as_uint(f);
  u += 0x7FFFu + ((u >> 16) & 1u);
  return (unsigned short)(u >> 16);
}
DI float bf2f(unsigned short h) { return __uint_as_float(((unsigned)h) << 16); }

DI f32x4 mfma_bf16(s16x8 a, s16x8 b, f32x4 c) {
  return __builtin_amdgcn_mfma_f32_16x16x32_bf16(a, b, c, 0, 0, 0);
}

DI float fast_tanh(float x) {
  float a = fminf(fabsf(x), 20.0f);
  float e = __expf(-2.0f * a);
  float r = (1.0f - e) / (1.0f + e);
  return __builtin_copysignf(r, x);
}

// ---------------- convert f32 weights -> bf16 in ws ----------------
__global__ __launch_bounds__(256) void k_convert(
    const float* __restrict__ emb, const float* __restrict__ uw,
    const float* __restrict__ vw,  const float* __restrict__ dw,
    unsigned short* __restrict__ embb, unsigned short* __restrict__ uwb,
    unsigned short* __restrict__ vwb,  unsigned short* __restrict__ dwb)
{
  int i = (blockIdx.x * 256 + threadIdx.x) * 4;   // 1966080 elems total, grid exact
  const float* s; unsigned short* d; int off;
  if      (i < 131072)  { s = emb; d = embb; off = i; }
  else if (i < 655360)  { s = uw;  d = uwb;  off = i - 131072; }
  else if (i < 1703936) { s = vw;  d = vwb;  off = i - 655360; }
  else                  { s = dw;  d = dwb;  off = i - 1703936; }
  float4 v = *(const float4*)(s + off);
  ushort4 o; o.x = f2bf(v.x); o.y = f2bf(v.y); o.z = f2bf(v.z); o.w = f2bf(v.w);
  *(ushort4*)(d + off) = o;
}

// ---------------- generic bf16 MFMA GEMM: C[r, n] = sum_k A[r,k]*B[n,k] ----------------
template<int KD, int NT, bool GATHER, bool OUTF32>
__global__ __launch_bounds__(256) void k_gemm(
    const unsigned short* __restrict__ Asrc,
    const int* __restrict__ xidx,
    const unsigned short* __restrict__ Bsrc,
    const float* __restrict__ biasv,
    unsigned short* __restrict__ Cb,
    float* __restrict__ Cf)
{
  __shared__ unsigned char As[64 * 128];
  __shared__ unsigned char Bs[64 * 128];
  __shared__ int xs[64];

  const int tid = threadIdx.x;
  const int rt = blockIdx.x, ct = blockIdx.y;
  const int r0 = rt * 64, c0 = ct * 64;

  if (GATHER) {
    if (tid < 64) xs[tid] = xidx[r0 + tid];
    __syncthreads();
  }

  const int r  = tid >> 2, kq = tid & 3;
  const unsigned short* aRow = GATHER ? (Asrc + (size_t)xs[r] * KD)
                                      : (Asrc + (size_t)(r0 + r) * KD);
  const unsigned short* bRow = Bsrc + (size_t)(c0 + r) * KD;
  const int dstOff = r * 128 + ((kq * 16) ^ ((r & 7) << 4));

  const int wave = tid >> 6, lane = tid & 63;
  const int ln15 = lane & 15, lg = lane >> 4;
  const int xr = (lane & 7) << 4;
  int aOff[4];
#pragma unroll
  for (int m = 0; m < 4; ++m) aOff[m] = (m * 16 + ln15) * 128 + ((lg * 16) ^ xr);
  const int bOff = (wave * 16 + ln15) * 128 + ((lg * 16) ^ xr);

  f32x4 acc[4] = {};
  for (int kk = 0; kk < KD / 32; ++kk) {
    s16x8 av = *(const s16x8*)(aRow + kk * 32 + kq * 8);
    s16x8 bv = *(const s16x8*)(bRow + kk * 32 + kq * 8);
    __syncthreads();
    *(s16x8*)(As + dstOff) = av;
    *(s16x8*)(Bs + dstOff) = bv;
    __syncthreads();
    s16x8 bf = *(const s16x8*)(Bs + bOff);
#pragma unroll
    for (int m = 0; m < 4; ++m) {
      s16x8 af = *(const s16x8*)(As + aOff[m]);
      acc[m] = mfma_bf16(af, bf, acc[m]);
    }
  }

  const int colg = c0 + wave * 16 + ln15;
  float bv = 0.f;
  if (OUTF32) bv = biasv[colg];
#pragma unroll
  for (int m = 0; m < 4; ++m) {
#pragma unroll
    for (int rr = 0; rr < 4; ++rr) {
      int rowg = r0 + m * 16 + lg * 4 + rr;
      if (OUTF32) Cf[(size_t)rowg * NT + colg] = acc[m][rr] + bv;
      else        Cb[(size_t)rowg * NT + colg] = f2bf(acc[m][rr]);
    }
  }
}

// ---------- persistent recurrence, v10: per-producer-WAVE epoch flags ----------
// 64 wgs x 256 thr. wg=(bg,cs): batches bg*16..+16, cols cs*64..+64.
// Best-of-all-rounds consolidation:
//  - V_w pinned in 128 VGPR/wave (R5); swapped MFMA mapping, 8B produce (R8/R9);
//    LDS-dedup'd staging + 4-chain MFMA (R5-R9); sc0sc1 exchange, no fences (R2+).
//  - Sync: 64 per-WAVE epoch flags per group. Producer wave: produce store ->
//    wave-level vmcnt(0) -> lane0 flag store. NO producer-side syncthreads,
//    no tid0 funnel. Consumer wave: busy-poll (no s_sleep) all 64 flags
//    lane-parallel + __all. Monotonic epochs -> hang-free; flag>=t+1 from all
//    waves proves h(t-1) readers done -> slot overwrite safe (R6 invariant).
//  - One syncthreads/step (post-staging LDS join) is all that remains.
__global__ __launch_bounds__(256, 1) void k_rec(
    const unsigned short* __restrict__ vwb,   // [H][H] bf16
    const unsigned short* __restrict__ ux,    // [B][L][H] bf16
    unsigned short* __restrict__ ring,        // [2][B][H] bf16
    unsigned short* __restrict__ hs,          // [B][L][H] bf16
    const float* __restrict__ alpha, const float* __restrict__ beta1,
    const float* __restrict__ beta2, const float* __restrict__ bias,
    float* __restrict__ out, int* flags)
{
  __shared__ __align__(16) unsigned char hlds[2][16 * 2048];   // 2 x 32 KiB

  const int w = blockIdx.x;
  const int bg = w >> 4, cs = w & 15;       // batch-group, col-slice
  const int tid = threadIdx.x;
  const int wave = tid >> 6, lane = tid & 63;
  const int ln15 = lane & 15, lg = lane >> 4;
  const int b0 = bg * 16;
  // swapped-operand mapping (validated R8/R9): lane's batch = b0+ln15;
  // lane's 4 contiguous V-cols = colbase..+3
  const int colbase = cs * 64 + wave * 16 + lg * 4;
  const int myb = b0 + ln15;

  // A-operand resident: breg[kc] lane l = V_w[cs*64+wave*16+(l&15)][kc*32+(l>>4)*8..+8]
  s16x8 breg[32];
  {
    const unsigned short* vrow = vwb + (size_t)(cs * 64 + wave * 16 + ln15) * CH + lg * 8;
#pragma unroll
    for (int kc = 0; kc < 32; ++kc) breg[kc] = *(const s16x8*)(vrow + kc * 32);
  }
#pragma unroll
  for (int kc = 0; kc < 32; ++kc) asm volatile("" : "+v"(breg[kc]));  // pin (R5 win)

  const float4 alv = *(const float4*)(alpha + colbase);
  const float4 b1v = *(const float4*)(beta1 + colbase);
  const float4 b2v = *(const float4*)(beta2 + colbase);
  const float4 biv = *(const float4*)(bias  + colbase);

  // ring descriptor; all ring traffic aux=17 (SC0|SC1): L1/L2-bypass, L3-coherent
  __amdgpu_buffer_rsrc_t rsrd = __builtin_amdgcn_make_buffer_rsrc(
      (void*)ring, (short)0, (int)(2u * SLOT), 0x00020000);

  // per-wave flag: group's 64 waves at flags[bg*64 + cs*4 + wave]
  int* gflags = flags + bg * 64;
  const int myflag = cs * 4 + wave;

  // staging (R6/R9-validated): thread stages 8 x 16B
  // LDS identity: hlds[row][col ^ ((row&7)<<4)] = ring_slot[b0+row][col]
  int sRow[8], sCol[8];
#pragma unroll
  for (int i = 0; i < 8; ++i) {
    const int L = i * 4096 + tid * 16;
    sRow[i] = L >> 11;
    sCol[i] = (L & 2047) ^ ((sRow[i] & 7) << 4);
  }
  const unsigned stgBase = (unsigned)(b0 * 2048);

  // fragment reads (B = h): LDS row ln15, k-chunk lg*8 (+kc*32)
  const int fBase = ln15 * 2048;
  const int fXor  = (ln15 & 7) << 4;

  // my produced cell offset within a slot (bytes): 8B, 4 contiguous cols
  const unsigned cellOff = (unsigned)(myb * 2048 + colbase * 2);

  s16x4 uxv = *(const s16x4*)(ux + ((size_t)myb * CL + 0) * CH + colbase);

  for (int t = 0; t < CL; ++t) {
    f32x4 vh = {};
    if (t > 0) {
      // ---- busy-poll all 64 producer-wave flags, lane-parallel ----
      bool ok;
      do {
        int fv = __hip_atomic_load(&gflags[lane], __ATOMIC_RELAXED,
                                   __HIP_MEMORY_SCOPE_SYSTEM);
        ok = __all(fv >= t) != 0;
      } while (!ok);
      asm volatile("" ::: "memory");        // no hoisting of data loads above poll

      // ---- stage h(t-1) slice from slot (t-1)&1 into LDS ----
      const unsigned roff = ((unsigned)((t - 1) & 1)) * SLOT + stgBase;
      s16x8 stg[8];
#pragma unroll
      for (int i = 0; i < 8; ++i) {
        auto raw = __builtin_amdgcn_raw_buffer_load_b128(
            rsrd, (int)(roff + i * 4096 + tid * 16), 0, 17);
        stg[i] = __builtin_bit_cast(s16x8, raw);
      }
      unsigned char* lb = hlds[t & 1];
#pragma unroll
      for (int i = 0; i < 8; ++i)
        *(s16x8*)(lb + sRow[i] * 2048 + sCol[i]) = stg[i];
      __syncthreads();                      // the ONE join per step

      // ---- fragments + MFMA, A=V_w (resident), B=h, 4 chains ----
      f32x4 a0 = {}, a1 = {}, a2 = {}, a3 = {};
#pragma unroll
      for (int kc = 0; kc < 32; kc += 4) {
        s16x8 f0 = *(const s16x8*)(lb + fBase + ((lg * 16 + kc * 64)       ^ fXor));
        s16x8 f1 = *(const s16x8*)(lb + fBase + ((lg * 16 + kc * 64 + 64)  ^ fXor));
        s16x8 f2 = *(const s16x8*)(lb + fBase + ((lg * 16 + kc * 64 + 128) ^ fXor));
        s16x8 f3 = *(const s16x8*)(lb + fBase + ((lg * 16 + kc * 64 + 192) ^ fXor));
        a0 = mfma_bf16(breg[kc],     f0, a0);
        a1 = mfma_bf16(breg[kc + 1], f1, a1);
        a2 = mfma_bf16(breg[kc + 2], f2, a2);
        a3 = mfma_bf16(breg[kc + 3], f3, a3);
      }
      vh = (a0 + a1) + (a2 + a3);
    }

    // ---- pointwise ----
    float hnv[4]; unsigned short hbv[4];
#pragma unroll
    for (int rr = 0; rr < 4; ++rr) {
      const float u = bf2f((unsigned short)uxv[rr]);
      const float v = vh[rr];
      const float mm = (&alv.x)[rr] * (v * u) + (&b1v.x)[rr] * v +
                       (&b2v.x)[rr] * u + (&biv.x)[rr];
      hnv[rr] = fast_tanh(mm);
      hbv[rr] = f2bf(hnv[rr]);
    }

    const unsigned long long pk = (unsigned long long)hbv[0]
                                | ((unsigned long long)hbv[1] << 16)
                                | ((unsigned long long)hbv[2] << 32)
                                | ((unsigned long long)hbv[3] << 48);

    if (t < CL - 1) {
      // produce: ONE 8B sc0sc1 store into slot t&1
      unsigned long long* hp = (unsigned long long*)
          ((char*)ring + (size_t)(t & 1) * SLOT + cellOff);
      __hip_atomic_store(hp, pk, __ATOMIC_RELAXED, __HIP_MEMORY_SCOPE_SYSTEM);
      // wave-level release: drain my produce store, then publish my wave flag
      asm volatile("s_waitcnt vmcnt(0)" ::: "memory");
      if (lane == 0)
        __hip_atomic_store(&gflags[myflag], t + 1, __ATOMIC_RELAXED,
                           __HIP_MEMORY_SCOPE_SYSTEM);
      // off critical path: hs persist + next ux prefetch (normal cached)
      *(unsigned long long*)(hs + ((size_t)myb * CL + t) * CH + colbase) = pk;
      uxv = *(const s16x4*)(ux + ((size_t)myb * CL + (t + 1)) * CH + colbase);
    } else {
      // last step: no consumer — just persist + final-h output
      *(unsigned long long*)(hs + ((size_t)myb * CL + t) * CH + colbase) = pk;
      float4 o; o.x = hnv[0]; o.y = hnv[1]; o.z = hnv[2]; o.w = hnv[3];
      *(float4*)(out + LOGN + (size_t)myb * CH + colbase) = o;
    }
  }
}

extern "C" void kernel_launch(void* const* d_in, const int* in_sizes, int n_in,
                              void* d_out, int out_size, void* d_ws, size_t ws_size,
                              hipStream_t stream) {
  const int*   x     = (const int*)  d_in[0];
  const float* emb   = (const float*)d_in[1];
  const float* Uw    = (const float*)d_in[2];
  const float* Vw    = (const float*)d_in[3];
  const float* alpha = (const float*)d_in[4];
  const float* beta1 = (const float*)d_in[5];
  const float* beta2 = (const float*)d_in[6];
  const float* bias  = (const float*)d_in[7];
  const float* decw  = (const float*)d_in[8];
  const float* decb  = (const float*)d_in[9];
  float* out = (float*)d_out;
  char*  ws  = (char*)d_ws;

  int*            flags = (int*)(ws + WS_BAR);
  unsigned short* ring  = (unsigned short*)(ws + WS_RING);
  unsigned short* embb  = (unsigned short*)(ws + WS_EMBB);
  unsigned short* uwb   = (unsigned short*)(ws + WS_UWB);
  unsigned short* vwb   = (unsigned short*)(ws + WS_VWB);
  unsigned short* dwb   = (unsigned short*)(ws + WS_DECWB);
  unsigned short* uxb   = (unsigned short*)(ws + WS_UX);
  unsigned short* hsb   = (unsigned short*)(ws + WS_HS);

  (void)hipMemsetAsync(ws + WS_BAR, 0, 4096, stream);   // reset epoch flags

  k_convert<<<1920, 256, 0, stream>>>(emb, Uw, Vw, decw, embb, uwb, vwb, dwb);

  k_gemm<CE, CH, true, false><<<dim3(CBL / 64, CH / 64), 256, 0, stream>>>(
      embb, x, uwb, nullptr, uxb, nullptr);

  k_rec<<<64, 256, 0, stream>>>(vwb, uxb, ring, hsb, alpha, beta1, beta2, bias, out, flags);

  k_gemm<CH, CV, false, true><<<dim3(CBL / 64, CV / 64), 256, 0, stream>>>(
      hsb, nullptr, dwb, decb, nullptr, out);
}

// Round 12
// 1478.977 us; speedup vs baseline: 1.2526x; 1.1025x over previous
//
#include <hip/hip_runtime.h>

#define DI __device__ __forceinline__

typedef short s16x4 __attribute__((ext_vector_type(4)));
typedef short s16x8 __attribute__((ext_vector_type(8)));
typedef float f32x4 __attribute__((ext_vector_type(4)));

constexpr int CB = 64, CL = 512, CV = 256, CE = 512, CH = 1024;
constexpr int CBL = CB * CL;                // 32768
constexpr size_t LOGN = (size_t)CBL * CV;   // 8388608 floats of logits
constexpr unsigned SLOT = (unsigned)CB * CH * 2;   // 128 KiB per ring slot

// ---- workspace layout (bytes) ----
constexpr size_t WS_BAR   = 0;                              // flags: 4 groups x 64 ints (1 KiB)
constexpr size_t WS_XCDT  = 1024;                           // xcd table: 4 x 16 ints
constexpr size_t WS_RING  = 4096;                           // 2-slot ring: 256 KiB
constexpr size_t WS_EMBB  = WS_RING + 2u*SLOT;              // emb bf16   256*512*2
constexpr size_t WS_UWB   = WS_EMBB + (size_t)CV*CE*2;      // U_w bf16   1024*512*2
constexpr size_t WS_VWB   = WS_UWB  + (size_t)CH*CE*2;      // V_w bf16   1024*1024*2
constexpr size_t WS_DECWB = WS_VWB  + (size_t)CH*CH*2;      // dec_w bf16 256*1024*2
constexpr size_t WS_UX    = WS_DECWB+ (size_t)CV*CH*2;      // Ux bf16    32768*1024*2
constexpr size_t WS_HS    = WS_UX   + (size_t)CBL*CH*2;     // hs bf16    32768*1024*2

DI unsigned short f2bf(float f) {            // RNE f32 -> bf16
  unsigned u = __float_as_uint(f);
  u += 0x7FFFu + ((u >> 16) & 1u);
  return (unsigned short)(u >> 16);
}
DI float bf2f(unsigned short h) { return __uint_as_float(((unsigned)h) << 16); }

DI f32x4 mfma_bf16(s16x8 a, s16x8 b, f32x4 c) {
  return __builtin_amdgcn_mfma_f32_16x16x32_bf16(a, b, c, 0, 0, 0);
}

DI float fast_tanh(float x) {
  float a = fminf(fabsf(x), 20.0f);
  float e = __expf(-2.0f * a);
  float r = (1.0f - e) / (1.0f + e);
  return __builtin_copysignf(r, x);
}

// ---------------- convert f32 weights -> bf16 in ws ----------------
__global__ __launch_bounds__(256) void k_convert(
    const float* __restrict__ emb, const float* __restrict__ uw,
    const float* __restrict__ vw,  const float* __restrict__ dw,
    unsigned short* __restrict__ embb, unsigned short* __restrict__ uwb,
    unsigned short* __restrict__ vwb,  unsigned short* __restrict__ dwb)
{
  int i = (blockIdx.x * 256 + threadIdx.x) * 4;   // 1966080 elems total, grid exact
  const float* s; unsigned short* d; int off;
  if      (i < 131072)  { s = emb; d = embb; off = i; }
  else if (i < 655360)  { s = uw;  d = uwb;  off = i - 131072; }
  else if (i < 1703936) { s = vw;  d = vwb;  off = i - 655360; }
  else                  { s = dw;  d = dwb;  off = i - 1703936; }
  float4 v = *(const float4*)(s + off);
  ushort4 o; o.x = f2bf(v.x); o.y = f2bf(v.y); o.z = f2bf(v.z); o.w = f2bf(v.w);
  *(ushort4*)(d + off) = o;
}

// ---------------- generic bf16 MFMA GEMM: C[r, n] = sum_k A[r,k]*B[n,k] ----------------
template<int KD, int NT, bool GATHER, bool OUTF32>
__global__ __launch_bounds__(256) void k_gemm(
    const unsigned short* __restrict__ Asrc,
    const int* __restrict__ xidx,
    const unsigned short* __restrict__ Bsrc,
    const float* __restrict__ biasv,
    unsigned short* __restrict__ Cb,
    float* __restrict__ Cf)
{
  __shared__ unsigned char As[64 * 128];
  __shared__ unsigned char Bs[64 * 128];
  __shared__ int xs[64];

  const int tid = threadIdx.x;
  const int rt = blockIdx.x, ct = blockIdx.y;
  const int r0 = rt * 64, c0 = ct * 64;

  if (GATHER) {
    if (tid < 64) xs[tid] = xidx[r0 + tid];
    __syncthreads();
  }

  const int r  = tid >> 2, kq = tid & 3;
  const unsigned short* aRow = GATHER ? (Asrc + (size_t)xs[r] * KD)
                                      : (Asrc + (size_t)(r0 + r) * KD);
  const unsigned short* bRow = Bsrc + (size_t)(c0 + r) * KD;
  const int dstOff = r * 128 + ((kq * 16) ^ ((r & 7) << 4));

  const int wave = tid >> 6, lane = tid & 63;
  const int ln15 = lane & 15, lg = lane >> 4;
  const int xr = (lane & 7) << 4;
  int aOff[4];
#pragma unroll
  for (int m = 0; m < 4; ++m) aOff[m] = (m * 16 + ln15) * 128 + ((lg * 16) ^ xr);
  const int bOff = (wave * 16 + ln15) * 128 + ((lg * 16) ^ xr);

  f32x4 acc[4] = {};
  for (int kk = 0; kk < KD / 32; ++kk) {
    s16x8 av = *(const s16x8*)(aRow + kk * 32 + kq * 8);
    s16x8 bv = *(const s16x8*)(bRow + kk * 32 + kq * 8);
    __syncthreads();
    *(s16x8*)(As + dstOff) = av;
    *(s16x8*)(Bs + dstOff) = bv;
    __syncthreads();
    s16x8 bf = *(const s16x8*)(Bs + bOff);
#pragma unroll
    for (int m = 0; m < 4; ++m) {
      s16x8 af = *(const s16x8*)(As + aOff[m]);
      acc[m] = mfma_bf16(af, bf, acc[m]);
    }
  }

  const int colg = c0 + wave * 16 + ln15;
  float bv = 0.f;
  if (OUTF32) bv = biasv[colg];
#pragma unroll
  for (int m = 0; m < 4; ++m) {
#pragma unroll
    for (int rr = 0; rr < 4; ++rr) {
      int rowg = r0 + m * 16 + lg * 4 + rr;
      if (OUTF32) Cf[(size_t)rowg * NT + colg] = acc[m][rr] + bv;
      else        Cb[(size_t)rowg * NT + colg] = f2bf(acc[m][rr]);
    }
  }
}

struct FastTag { static constexpr bool fast = true;  };
struct SafeTag { static constexpr bool fast = false; };

// -------- persistent recurrence, v11: XCD-local groups, L2-coherent exchange --------
// 128 wgs launched; role: bg=bid&7 (<4 else exit), cs=bid>>3. Under round-robin
// dispatch a group's 16 wgs share one XCD. One-time registration: each role wg
// publishes its ACTUAL XCC_ID; group verifies all-16-equal -> FAST mode
// (sc0-only = XCD-L2 coherent, ~250cy RT) else SAFE mode (sc0sc1 = L3, R10 path).
// Deadlock-free: roles are pure bid functions; both modes' invariants proven R10.
// Everything else = R10: V_w pinned 128 VGPR/wave, swapped MFMA, 8B produce,
// per-wave epoch flags, busy-poll, LDS-dedup staging, one syncthreads/step.
__global__ __launch_bounds__(256, 1) void k_rec(
    const unsigned short* __restrict__ vwb,   // [H][H] bf16
    const unsigned short* __restrict__ ux,    // [B][L][H] bf16
    unsigned short* __restrict__ ring,        // [2][B][H] bf16
    unsigned short* __restrict__ hs,          // [B][L][H] bf16
    const float* __restrict__ alpha, const float* __restrict__ beta1,
    const float* __restrict__ beta2, const float* __restrict__ bias,
    float* __restrict__ out, int* flags, int* xcdtab)
{
  __shared__ __align__(16) unsigned char hlds[2][16 * 2048];   // 2 x 32 KiB
  __shared__ int smode;

  const int bid = blockIdx.x;
  const int bg = bid & 7, cs = bid >> 3;
  if (bg >= 4) return;                      // 64 spare wgs exit (uniform per wg)
  const int tid = threadIdx.x;
  const int wave = tid >> 6, lane = tid & 63;
  const int ln15 = lane & 15, lg = lane >> 4;
  const int b0 = bg * 16;
  const int colbase = cs * 64 + wave * 16 + lg * 4;
  const int myb = b0 + ln15;

  // ---- one-time registration + mode select (sc1, off steady-state path) ----
  int* gxt = xcdtab + bg * 16;
  if (tid == 0) {
    unsigned myxcd;
    asm volatile("s_getreg_b32 %0, hwreg(HW_REG_XCC_ID)" : "=s"(myxcd));
    myxcd &= 15u;
    __hip_atomic_store(&gxt[cs], (int)myxcd, __ATOMIC_RELAXED, __HIP_MEMORY_SCOPE_SYSTEM);
    int first = -1; bool same = true;
    for (int i = 0; i < 16;) {
      int v = __hip_atomic_load(&gxt[i], __ATOMIC_RELAXED, __HIP_MEMORY_SCOPE_SYSTEM);
      if (v == -1) { __builtin_amdgcn_s_sleep(8); continue; }
      if (first == -1) first = v; else if (v != first) same = false;
      ++i;
    }
    smode = same ? 1 : 0;
  }
  __syncthreads();
  const bool fastmode = (smode != 0);

  // A-operand resident: breg[kc] lane l = V_w[cs*64+wave*16+(l&15)][kc*32+(l>>4)*8..+8]
  s16x8 breg[32];
  {
    const unsigned short* vrow = vwb + (size_t)(cs * 64 + wave * 16 + ln15) * CH + lg * 8;
#pragma unroll
    for (int kc = 0; kc < 32; ++kc) breg[kc] = *(const s16x8*)(vrow + kc * 32);
  }
#pragma unroll
  for (int kc = 0; kc < 32; ++kc) asm volatile("" : "+v"(breg[kc]));  // pin (R5 win)

  const float4 alv = *(const float4*)(alpha + colbase);
  const float4 b1v = *(const float4*)(beta1 + colbase);
  const float4 b2v = *(const float4*)(beta2 + colbase);
  const float4 biv = *(const float4*)(bias  + colbase);

  __amdgpu_buffer_rsrc_t rsrd = __builtin_amdgcn_make_buffer_rsrc(
      (void*)ring, (short)0, (int)(2u * SLOT), 0x00020000);

  int* gflags = flags + bg * 64;
  const int myflag = cs * 4 + wave;

  int sRow[8], sCol[8];
#pragma unroll
  for (int i = 0; i < 8; ++i) {
    const int L = i * 4096 + tid * 16;
    sRow[i] = L >> 11;
    sCol[i] = (L & 2047) ^ ((sRow[i] & 7) << 4);
  }
  const unsigned stgBase = (unsigned)(b0 * 2048);

  const int fBase = ln15 * 2048;
  const int fXor  = (ln15 & 7) << 4;
  const unsigned cellOff = (unsigned)(myb * 2048 + colbase * 2);

  s16x4 uxv = *(const s16x4*)(ux + ((size_t)myb * CL + 0) * CH + colbase);

  auto run = [&](auto tag) {
    // FAST: sc0 only (aux=1, AGENT) — coherent at the XCD's L2.
    // SAFE: sc0|sc1 (aux=17, SYSTEM) — coherent at L3 (R2-R10 proven).
    constexpr int  AUX = decltype(tag)::fast ? 1 : 17;
    constexpr auto SCP = decltype(tag)::fast ? __HIP_MEMORY_SCOPE_AGENT
                                             : __HIP_MEMORY_SCOPE_SYSTEM;
    for (int t = 0; t < CL; ++t) {
      f32x4 vh = {};
      if (t > 0) {
        // busy-poll all 64 producer-wave flags, lane-parallel
        bool ok;
        do {
          int fv = __hip_atomic_load(&gflags[lane], __ATOMIC_RELAXED, SCP);
          ok = __all(fv >= t) != 0;
        } while (!ok);
        asm volatile("" ::: "memory");

        // stage h(t-1) slice from slot (t-1)&1 into LDS (L1-bypassing loads)
        const unsigned roff = ((unsigned)((t - 1) & 1)) * SLOT + stgBase;
        s16x8 stg[8];
#pragma unroll
        for (int i = 0; i < 8; ++i) {
          auto raw = __builtin_amdgcn_raw_buffer_load_b128(
              rsrd, (int)(roff + i * 4096 + tid * 16), 0, AUX);
          stg[i] = __builtin_bit_cast(s16x8, raw);
        }
        unsigned char* lb = hlds[t & 1];
#pragma unroll
        for (int i = 0; i < 8; ++i)
          *(s16x8*)(lb + sRow[i] * 2048 + sCol[i]) = stg[i];
        __syncthreads();                    // the ONE join per step

        // fragments + MFMA, A=V_w (resident), B=h, 4 chains
        f32x4 a0 = {}, a1 = {}, a2 = {}, a3 = {};
#pragma unroll
        for (int kc = 0; kc < 32; kc += 4) {
          s16x8 f0 = *(const s16x8*)(lb + fBase + ((lg * 16 + kc * 64)       ^ fXor));
          s16x8 f1 = *(const s16x8*)(lb + fBase + ((lg * 16 + kc * 64 + 64)  ^ fXor));
          s16x8 f2 = *(const s16x8*)(lb + fBase + ((lg * 16 + kc * 64 + 128) ^ fXor));
          s16x8 f3 = *(const s16x8*)(lb + fBase + ((lg * 16 + kc * 64 + 192) ^ fXor));
          a0 = mfma_bf16(breg[kc],     f0, a0);
          a1 = mfma_bf16(breg[kc + 1], f1, a1);
          a2 = mfma_bf16(breg[kc + 2], f2, a2);
          a3 = mfma_bf16(breg[kc + 3], f3, a3);
        }
        vh = (a0 + a1) + (a2 + a3);
      }

      // pointwise
      float hnv[4]; unsigned short hbv[4];
#pragma unroll
      for (int rr = 0; rr < 4; ++rr) {
        const float u = bf2f((unsigned short)uxv[rr]);
        const float v = vh[rr];
        const float mm = (&alv.x)[rr] * (v * u) + (&b1v.x)[rr] * v +
                         (&b2v.x)[rr] * u + (&biv.x)[rr];
        hnv[rr] = fast_tanh(mm);
        hbv[rr] = f2bf(hnv[rr]);
      }

      const unsigned long long pk = (unsigned long long)hbv[0]
                                  | ((unsigned long long)hbv[1] << 16)
                                  | ((unsigned long long)hbv[2] << 32)
                                  | ((unsigned long long)hbv[3] << 48);

      if (t < CL - 1) {
        // produce: ONE 8B store into slot t&1 (FAST: lands in local L2)
        unsigned long long* hp = (unsigned long long*)
            ((char*)ring + (size_t)(t & 1) * SLOT + cellOff);
        __hip_atomic_store(hp, pk, __ATOMIC_RELAXED, SCP);
        // wave-level release: drain produce, then publish wave flag
        asm volatile("s_waitcnt vmcnt(0)" ::: "memory");
        if (lane == 0)
          __hip_atomic_store(&gflags[myflag], t + 1, __ATOMIC_RELAXED, SCP);
        // off critical path: hs persist + next ux prefetch (normal cached)
        *(unsigned long long*)(hs + ((size_t)myb * CL + t) * CH + colbase) = pk;
        uxv = *(const s16x4*)(ux + ((size_t)myb * CL + (t + 1)) * CH + colbase);
      } else {
        *(unsigned long long*)(hs + ((size_t)myb * CL + t) * CH + colbase) = pk;
        float4 o; o.x = hnv[0]; o.y = hnv[1]; o.z = hnv[2]; o.w = hnv[3];
        *(float4*)(out + LOGN + (size_t)myb * CH + colbase) = o;
      }
    }
  };
  if (fastmode) run(FastTag{}); else run(SafeTag{});
}

extern "C" void kernel_launch(void* const* d_in, const int* in_sizes, int n_in,
                              void* d_out, int out_size, void* d_ws, size_t ws_size,
                              hipStream_t stream) {
  const int*   x     = (const int*)  d_in[0];
  const float* emb   = (const float*)d_in[1];
  const float* Uw    = (const float*)d_in[2];
  const float* Vw    = (const float*)d_in[3];
  const float* alpha = (const float*)d_in[4];
  const float* beta1 = (const float*)d_in[5];
  const float* beta2 = (const float*)d_in[6];
  const float* bias  = (const float*)d_in[7];
  const float* decw  = (const float*)d_in[8];
  const float* decb  = (const float*)d_in[9];
  float* out = (float*)d_out;
  char*  ws  = (char*)d_ws;

  int*            flags = (int*)(ws + WS_BAR);
  int*            xcdt  = (int*)(ws + WS_XCDT);
  unsigned short* ring  = (unsigned short*)(ws + WS_RING);
  unsigned short* embb  = (unsigned short*)(ws + WS_EMBB);
  unsigned short* uwb   = (unsigned short*)(ws + WS_UWB);
  unsigned short* vwb   = (unsigned short*)(ws + WS_VWB);
  unsigned short* dwb   = (unsigned short*)(ws + WS_DECWB);
  unsigned short* uxb   = (unsigned short*)(ws + WS_UX);
  unsigned short* hsb   = (unsigned short*)(ws + WS_HS);

  (void)hipMemsetAsync(ws + WS_BAR, 0, 1024, stream);        // epoch flags = 0
  (void)hipMemsetAsync(ws + WS_XCDT, 0xFF, 256, stream);     // xcd table = -1

  k_convert<<<1920, 256, 0, stream>>>(emb, Uw, Vw, decw, embb, uwb, vwb, dwb);

  k_gemm<CE, CH, true, false><<<dim3(CBL / 64, CH / 64), 256, 0, stream>>>(
      embb, x, uwb, nullptr, uxb, nullptr);

  k_rec<<<128, 256, 0, stream>>>(vwb, uxb, ring, hsb, alpha, beta1, beta2, bias,
                                 out, flags, xcdt);

  k_gemm<CH, CV, false, true><<<dim3(CBL / 64, CV / 64), 256, 0, stream>>>(
      hsb, nullptr, dwb, decb, nullptr, out);
}

// Round 13
// 1442.732 us; speedup vs baseline: 1.2841x; 1.0251x over previous
//
#include <hip/hip_runtime.h>

#define DI __device__ __forceinline__

typedef short s16x4 __attribute__((ext_vector_type(4)));
typedef short s16x8 __attribute__((ext_vector_type(8)));
typedef float f32x4 __attribute__((ext_vector_type(4)));

constexpr int CB = 64, CL = 512, CV = 256, CE = 512, CH = 1024;
constexpr int CBL = CB * CL;                // 32768
constexpr size_t LOGN = (size_t)CBL * CV;   // 8388608 floats of logits
constexpr unsigned SLOT = (unsigned)CB * CH * 2;   // 128 KiB per ring slot

// ---- workspace layout (bytes) ----
constexpr size_t WS_BAR   = 0;                              // flags: 4 groups x 64 ints (1 KiB)
constexpr size_t WS_XCDT  = 1024;                           // xcd table: 4 x 16 ints
constexpr size_t WS_RING  = 4096;                           // 2-slot ring: 256 KiB
constexpr size_t WS_EMBB  = WS_RING + 2u*SLOT;              // emb bf16   256*512*2
constexpr size_t WS_UWB   = WS_EMBB + (size_t)CV*CE*2;      // U_w bf16   1024*512*2
constexpr size_t WS_VWB   = WS_UWB  + (size_t)CH*CE*2;      // V_w bf16   1024*1024*2
constexpr size_t WS_DECWB = WS_VWB  + (size_t)CH*CH*2;      // dec_w bf16 256*1024*2
constexpr size_t WS_UX    = WS_DECWB+ (size_t)CV*CH*2;      // Ux bf16    32768*1024*2
constexpr size_t WS_HS    = WS_UX   + (size_t)CBL*CH*2;     // hs bf16    32768*1024*2

DI unsigned short f2bf(float f) {            // RNE f32 -> bf16
  unsigned u = __float_as_uint(f);
  u += 0x7FFFu + ((u >> 16) & 1u);
  return (unsigned short)(u >> 16);
}
DI float bf2f(unsigned short h) { return __uint_as_float(((unsigned)h) << 16); }

DI f32x4 mfma_bf16(s16x8 a, s16x8 b, f32x4 c) {
  return __builtin_amdgcn_mfma_f32_16x16x32_bf16(a, b, c, 0, 0, 0);
}

DI float fast_tanh(float x) {
  float a = fminf(fabsf(x), 20.0f);
  float e = __expf(-2.0f * a);
  float r = (1.0f - e) / (1.0f + e);
  return __builtin_copysignf(r, x);
}

// ---------------- convert f32 weights -> bf16 in ws ----------------
__global__ __launch_bounds__(256) void k_convert(
    const float* __restrict__ emb, const float* __restrict__ uw,
    const float* __restrict__ vw,  const float* __restrict__ dw,
    unsigned short* __restrict__ embb, unsigned short* __restrict__ uwb,
    unsigned short* __restrict__ vwb,  unsigned short* __restrict__ dwb)
{
  int i = (blockIdx.x * 256 + threadIdx.x) * 4;   // 1966080 elems total, grid exact
  const float* s; unsigned short* d; int off;
  if      (i < 131072)  { s = emb; d = embb; off = i; }
  else if (i < 655360)  { s = uw;  d = uwb;  off = i - 131072; }
  else if (i < 1703936) { s = vw;  d = vwb;  off = i - 655360; }
  else                  { s = dw;  d = dwb;  off = i - 1703936; }
  float4 v = *(const float4*)(s + off);
  ushort4 o; o.x = f2bf(v.x); o.y = f2bf(v.y); o.z = f2bf(v.z); o.w = f2bf(v.w);
  *(ushort4*)(d + off) = o;
}

// ---------------- generic bf16 MFMA GEMM: C[r, n] = sum_k A[r,k]*B[n,k] ----------------
template<int KD, int NT, bool GATHER, bool OUTF32>
__global__ __launch_bounds__(256) void k_gemm(
    const unsigned short* __restrict__ Asrc,
    const int* __restrict__ xidx,
    const unsigned short* __restrict__ Bsrc,
    const float* __restrict__ biasv,
    unsigned short* __restrict__ Cb,
    float* __restrict__ Cf)
{
  __shared__ unsigned char As[64 * 128];
  __shared__ unsigned char Bs[64 * 128];
  __shared__ int xs[64];

  const int tid = threadIdx.x;
  const int rt = blockIdx.x, ct = blockIdx.y;
  const int r0 = rt * 64, c0 = ct * 64;

  if (GATHER) {
    if (tid < 64) xs[tid] = xidx[r0 + tid];
    __syncthreads();
  }

  const int r  = tid >> 2, kq = tid & 3;
  const unsigned short* aRow = GATHER ? (Asrc + (size_t)xs[r] * KD)
                                      : (Asrc + (size_t)(r0 + r) * KD);
  const unsigned short* bRow = Bsrc + (size_t)(c0 + r) * KD;
  const int dstOff = r * 128 + ((kq * 16) ^ ((r & 7) << 4));

  const int wave = tid >> 6, lane = tid & 63;
  const int ln15 = lane & 15, lg = lane >> 4;
  const int xr = (lane & 7) << 4;
  int aOff[4];
#pragma unroll
  for (int m = 0; m < 4; ++m) aOff[m] = (m * 16 + ln15) * 128 + ((lg * 16) ^ xr);
  const int bOff = (wave * 16 + ln15) * 128 + ((lg * 16) ^ xr);

  f32x4 acc[4] = {};
  for (int kk = 0; kk < KD / 32; ++kk) {
    s16x8 av = *(const s16x8*)(aRow + kk * 32 + kq * 8);
    s16x8 bv = *(const s16x8*)(bRow + kk * 32 + kq * 8);
    __syncthreads();
    *(s16x8*)(As + dstOff) = av;
    *(s16x8*)(Bs + dstOff) = bv;
    __syncthreads();
    s16x8 bf = *(const s16x8*)(Bs + bOff);
#pragma unroll
    for (int m = 0; m < 4; ++m) {
      s16x8 af = *(const s16x8*)(As + aOff[m]);
      acc[m] = mfma_bf16(af, bf, acc[m]);
    }
  }

  const int colg = c0 + wave * 16 + ln15;
  float bv = 0.f;
  if (OUTF32) bv = biasv[colg];
#pragma unroll
  for (int m = 0; m < 4; ++m) {
#pragma unroll
    for (int rr = 0; rr < 4; ++rr) {
      int rowg = r0 + m * 16 + lg * 4 + rr;
      if (OUTF32) Cf[(size_t)rowg * NT + colg] = acc[m][rr] + bv;
      else        Cb[(size_t)rowg * NT + colg] = f2bf(acc[m][rr]);
    }
  }
}

struct FastTag { static constexpr bool fast = true;  };
struct SafeTag { static constexpr bool fast = false; };

// ---- persistent recurrence, v12: 512-thr wgs (2 waves/SIMD TLP), 8-wg groups ----
// 64 wgs launched; role: bg=bid&7 (<4 else exit), cs=bid>>3 (0..7, 128 cols each).
// Under round-robin a group's 8 wgs (bids == bg mod 8) share one XCD -> FAST
// mode (sc0, L2-coherent) after registration check; else SAFE (sc0sc1, L3).
// v12 changes vs R11: (1) 512-thread wgs -> 2 waves/SIMD latency hiding
// (was 1 wave/SIMD: every stall exposed); (2) LDS XOR swizzle widened to
// (row&15)<<4 on BOTH sides -> fragment reads conflict-free (rows are 2048B
// apart = bank-aliased; the old (row&7) left 2-way collisions, 1.67e7 cy);
// (3) join narrowed 16->8 wgs. Per-wave work/protocol/math unchanged (proven).
__global__ __launch_bounds__(512, 1) void k_rec(
    const unsigned short* __restrict__ vwb,   // [H][H] bf16
    const unsigned short* __restrict__ ux,    // [B][L][H] bf16
    unsigned short* __restrict__ ring,        // [2][B][H] bf16
    unsigned short* __restrict__ hs,          // [B][L][H] bf16
    const float* __restrict__ alpha, const float* __restrict__ beta1,
    const float* __restrict__ beta2, const float* __restrict__ bias,
    float* __restrict__ out, int* flags, int* xcdtab)
{
  __shared__ __align__(16) unsigned char hlds[2][16 * 2048];   // 2 x 32 KiB
  __shared__ int smode;

  const int bid = blockIdx.x;
  const int bg = bid & 7, cs = bid >> 3;    // batch-group, col-slice (128 cols)
  if (bg >= 4) return;                      // spare wgs exit
  const int tid = threadIdx.x;
  const int wave = tid >> 6, lane = tid & 63;
  const int ln15 = lane & 15, lg = lane >> 4;
  const int b0 = bg * 16;
  const int colbase = cs * 128 + wave * 16 + lg * 4;
  const int myb = b0 + ln15;

  // ---- one-time registration + mode select ----
  int* gxt = xcdtab + bg * 16;
  if (tid == 0) {
    unsigned myxcd;
    asm volatile("s_getreg_b32 %0, hwreg(HW_REG_XCC_ID)" : "=s"(myxcd));
    myxcd &= 15u;
    __hip_atomic_store(&gxt[cs], (int)myxcd, __ATOMIC_RELAXED, __HIP_MEMORY_SCOPE_SYSTEM);
    int first = -1; bool same = true;
    for (int i = 0; i < 8;) {
      int v = __hip_atomic_load(&gxt[i], __ATOMIC_RELAXED, __HIP_MEMORY_SCOPE_SYSTEM);
      if (v == -1) { __builtin_amdgcn_s_sleep(8); continue; }
      if (first == -1) first = v; else if (v != first) same = false;
      ++i;
    }
    smode = same ? 1 : 0;
  }
  __syncthreads();
  const bool fastmode = (smode != 0);

  // A-operand resident: breg[kc] lane l = V_w[colrow][kc*32+(l>>4)*8..+8]
  s16x8 breg[32];
  {
    const unsigned short* vrow = vwb + (size_t)(cs * 128 + wave * 16 + ln15) * CH + lg * 8;
#pragma unroll
    for (int kc = 0; kc < 32; ++kc) breg[kc] = *(const s16x8*)(vrow + kc * 32);
  }
#pragma unroll
  for (int kc = 0; kc < 32; ++kc) asm volatile("" : "+v"(breg[kc]));  // pin (R5 win)

  const float4 alv = *(const float4*)(alpha + colbase);
  const float4 b1v = *(const float4*)(beta1 + colbase);
  const float4 b2v = *(const float4*)(beta2 + colbase);
  const float4 biv = *(const float4*)(bias  + colbase);

  __amdgpu_buffer_rsrc_t rsrd = __builtin_amdgcn_make_buffer_rsrc(
      (void*)ring, (short)0, (int)(2u * SLOT), 0x00020000);

  int* gflags = flags + bg * 64;            // 64 wave-flags per group (8 wgs x 8 waves)
  const int myflag = cs * 8 + wave;

  // staging: 512 threads x 4 chunks x 16B = 32 KiB slice
  // LDS identity: hlds[row][col ^ ((row&15)<<4)] = ring_slot[b0+row][col]
  int sRow[4], sCol[4];
#pragma unroll
  for (int i = 0; i < 4; ++i) {
    const int L = i * 8192 + tid * 16;
    sRow[i] = L >> 11;
    sCol[i] = (L & 2047) ^ ((sRow[i] & 15) << 4);
  }
  const unsigned stgBase = (unsigned)(b0 * 2048);

  // fragment reads (B = h): row ln15, chunk (lg*16 + kc*64) ^ (ln15<<4)
  // -> for fixed (lg,kc) the 16 ln15 lanes hit 16 DISTINCT 16B slots: conflict-free
  const int fBase = ln15 * 2048;
  const int fXor  = ln15 << 4;
  const unsigned cellOff = (unsigned)(myb * 2048 + colbase * 2);

  s16x4 uxv = *(const s16x4*)(ux + ((size_t)myb * CL + 0) * CH + colbase);

  auto run = [&](auto tag) {
    constexpr int  AUX = decltype(tag)::fast ? 1 : 17;
    constexpr auto SCP = decltype(tag)::fast ? __HIP_MEMORY_SCOPE_AGENT
                                             : __HIP_MEMORY_SCOPE_SYSTEM;
    for (int t = 0; t < CL; ++t) {
      f32x4 vh = {};
      if (t > 0) {
        // busy-poll all 64 producer-wave flags, lane-parallel
        bool ok;
        do {
          int fv = __hip_atomic_load(&gflags[lane], __ATOMIC_RELAXED, SCP);
          ok = __all(fv >= t) != 0;
        } while (!ok);
        asm volatile("" ::: "memory");

        // stage h(t-1) slice from slot (t-1)&1 into LDS (4 chunks/thread)
        const unsigned roff = ((unsigned)((t - 1) & 1)) * SLOT + stgBase;
        s16x8 stg[4];
#pragma unroll
        for (int i = 0; i < 4; ++i) {
          auto raw = __builtin_amdgcn_raw_buffer_load_b128(
              rsrd, (int)(roff + i * 8192 + tid * 16), 0, AUX);
          stg[i] = __builtin_bit_cast(s16x8, raw);
        }
        unsigned char* lb = hlds[t & 1];
#pragma unroll
        for (int i = 0; i < 4; ++i)
          *(s16x8*)(lb + sRow[i] * 2048 + sCol[i]) = stg[i];
        __syncthreads();                    // the ONE join per step

        // fragments + MFMA, A=V_w (resident), B=h, 4 chains
        f32x4 a0 = {}, a1 = {}, a2 = {}, a3 = {};
#pragma unroll
        for (int kc = 0; kc < 32; kc += 4) {
          s16x8 f0 = *(const s16x8*)(lb + fBase + ((lg * 16 + kc * 64)       ^ fXor));
          s16x8 f1 = *(const s16x8*)(lb + fBase + ((lg * 16 + kc * 64 + 64)  ^ fXor));
          s16x8 f2 = *(const s16x8*)(lb + fBase + ((lg * 16 + kc * 64 + 128) ^ fXor));
          s16x8 f3 = *(const s16x8*)(lb + fBase + ((lg * 16 + kc * 64 + 192) ^ fXor));
          a0 = mfma_bf16(breg[kc],     f0, a0);
          a1 = mfma_bf16(breg[kc + 1], f1, a1);
          a2 = mfma_bf16(breg[kc + 2], f2, a2);
          a3 = mfma_bf16(breg[kc + 3], f3, a3);
        }
        vh = (a0 + a1) + (a2 + a3);
      }

      // pointwise
      float hnv[4]; unsigned short hbv[4];
#pragma unroll
      for (int rr = 0; rr < 4; ++rr) {
        const float u = bf2f((unsigned short)uxv[rr]);
        const float v = vh[rr];
        const float mm = (&alv.x)[rr] * (v * u) + (&b1v.x)[rr] * v +
                         (&b2v.x)[rr] * u + (&biv.x)[rr];
        hnv[rr] = fast_tanh(mm);
        hbv[rr] = f2bf(hnv[rr]);
      }

      const unsigned long long pk = (unsigned long long)hbv[0]
                                  | ((unsigned long long)hbv[1] << 16)
                                  | ((unsigned long long)hbv[2] << 32)
                                  | ((unsigned long long)hbv[3] << 48);

      if (t < CL - 1) {
        // produce: ONE 8B store into slot t&1
        unsigned long long* hp = (unsigned long long*)
            ((char*)ring + (size_t)(t & 1) * SLOT + cellOff);
        __hip_atomic_store(hp, pk, __ATOMIC_RELAXED, SCP);
        // wave-level release: drain produce, then publish wave flag
        asm volatile("s_waitcnt vmcnt(0)" ::: "memory");
        if (lane == 0)
          __hip_atomic_store(&gflags[myflag], t + 1, __ATOMIC_RELAXED, SCP);
        // off critical path: hs persist + next ux prefetch (normal cached)
        *(unsigned long long*)(hs + ((size_t)myb * CL + t) * CH + colbase) = pk;
        uxv = *(const s16x4*)(ux + ((size_t)myb * CL + (t + 1)) * CH + colbase);
      } else {
        *(unsigned long long*)(hs + ((size_t)myb * CL + t) * CH + colbase) = pk;
        float4 o; o.x = hnv[0]; o.y = hnv[1]; o.z = hnv[2]; o.w = hnv[3];
        *(float4*)(out + LOGN + (size_t)myb * CH + colbase) = o;
      }
    }
  };
  if (fastmode) run(FastTag{}); else run(SafeTag{});
}

extern "C" void kernel_launch(void* const* d_in, const int* in_sizes, int n_in,
                              void* d_out, int out_size, void* d_ws, size_t ws_size,
                              hipStream_t stream) {
  const int*   x     = (const int*)  d_in[0];
  const float* emb   = (const float*)d_in[1];
  const float* Uw    = (const float*)d_in[2];
  const float* Vw    = (const float*)d_in[3];
  const float* alpha = (const float*)d_in[4];
  const float* beta1 = (const float*)d_in[5];
  const float* beta2 = (const float*)d_in[6];
  const float* bias  = (const float*)d_in[7];
  const float* decw  = (const float*)d_in[8];
  const float* decb  = (const float*)d_in[9];
  float* out = (float*)d_out;
  char*  ws  = (char*)d_ws;

  int*            flags = (int*)(ws + WS_BAR);
  int*            xcdt  = (int*)(ws + WS_XCDT);
  unsigned short* ring  = (unsigned short*)(ws + WS_RING);
  unsigned short* embb  = (unsigned short*)(ws + WS_EMBB);
  unsigned short* uwb   = (unsigned short*)(ws + WS_UWB);
  unsigned short* vwb   = (unsigned short*)(ws + WS_VWB);
  unsigned short* dwb   = (unsigned short*)(ws + WS_DECWB);
  unsigned short* uxb   = (unsigned short*)(ws + WS_UX);
  unsigned short* hsb   = (unsigned short*)(ws + WS_HS);

  (void)hipMemsetAsync(ws + WS_BAR, 0, 1024, stream);        // epoch flags = 0
  (void)hipMemsetAsync(ws + WS_XCDT, 0xFF, 256, stream);     // xcd table = -1

  k_convert<<<1920, 256, 0, stream>>>(emb, Uw, Vw, decw, embb, uwb, vwb, dwb);

  k_gemm<CE, CH, true, false><<<dim3(CBL / 64, CH / 64), 256, 0, stream>>>(
      embb, x, uwb, nullptr, uxb, nullptr);

  k_rec<<<64, 512, 0, stream>>>(vwb, uxb, ring, hsb, alpha, beta1, beta2, bias,
                                out, flags, xcdt);

  k_gemm<CH, CV, false, true><<<dim3(CBL / 64, CV / 64), 256, 0, stream>>>(
      hsb, nullptr, dwb, decb, nullptr, out);
}